// Round 12
// baseline (15642.929 us; speedup 1.0000x reference)
//
#include <hip/hip_runtime.h>
#include <math.h>

#define B_      8
#define N_      16384
#define CIN_    128
#define COUT_   256
#define NS_     4096

// XLA-CPU-contracted distance: fma(dz,dz, fma(dy,dy, dx*dx)) — bit-exact vs gold.
static __device__ __forceinline__ float sqdist_xla(float px, float py, float pz,
                                                   float cx, float cy, float cz) {
  float dx = __fsub_rn(px, cx);
  float dy = __fsub_rn(py, cy);
  float dz = __fsub_rn(pz, cz);
  return __fmaf_rn(dz, dz, __fmaf_rn(dy, dy, __fmul_rn(dx, dx)));
}

// Blocks 0..7: FPS — xy staged in LDS (coalesced layout n = k*1024+tid),
// z streamed per-iteration via volatile coalesced loads, dd in registers.
// Blocks 8..15: full Gram G = F^T F + column sums S per batch (hidden under FPS).
__global__ __launch_bounds__(1024) void k1_fps_gram(
    const float* __restrict__ points, const float* __restrict__ features,
    float* __restrict__ outP, int* __restrict__ idxw,
    float* __restrict__ Gred, float* __restrict__ Sred)
{
  __shared__ __align__(16) char LDSB[131072 + 256];
  const int tid = threadIdx.x;

  if (blockIdx.x < B_) {
    // ================= FPS =================
    const int b = blockIdx.x;
    const float* __restrict__ P = points + (size_t)b * N_ * 3;
    const volatile float* Pv = P;          // per-iter z stream (no hoist, no remat-games)
    float2* __restrict__ sXY = (float2*)LDSB;
    float*  __restrict__ sv  = (float*)(LDSB + 131072);          // [2][16]
    int*    __restrict__ si  = (int*)  (LDSB + 131072 + 128);    // [2][16]
    float*  __restrict__ cent= (float*)(LDSB + 131072 + 240);
    const int lane = tid & 63;
    const int wid  = tid >> 6;    // 0..15

    // stage xy into LDS, coalesced (lane stride 12B)
    for (int k = 0; k < 16; ++k) {
      const int n = k * 1024 + tid;
      sXY[n] = make_float2(P[3*n+0], P[3*n+1]);
    }
    // centroid: strict sequential f32 (reference emission order), *2^-14 exact
    if (tid < 3) {
      const int c = tid;
      float acc = P[c];
      for (int n = 1; n < N_; ++n) acc = __fadd_rn(acc, P[3*n + c]);
      cent[c] = __fmul_rn(acc, 6.103515625e-05f);
    }
    __syncthreads();

    float dd[16];
    float ccx, ccy, ccz;
    int far;

    // wave (val,idx) reduce + parity-slot block reduce + uniform winner fetch.
    // tie-break: larger val, then smaller global index (== first occurrence).
    #define SELECT_FAR(pw, ss) do { \
      float wm = lm; int cand = gi; \
      _Pragma("unroll") \
      for (int off = 32; off > 0; off >>= 1) { \
        const float ov = __shfl_xor(wm, off); \
        const int   oi = __shfl_xor(cand, off); \
        const bool better = (ov > wm) || ((ov == wm) && (oi < cand)); \
        wm = better ? ov : wm; cand = better ? oi : cand; \
      } \
      if (lane == 0) { sv[(pw)*16 + wid] = wm; si[(pw)*16 + wid] = cand; } \
      __syncthreads(); \
      float bv = sv[(pw)*16]; int bi = si[(pw)*16]; \
      _Pragma("unroll") \
      for (int w = 1; w < 16; ++w) { \
        const float v = sv[(pw)*16 + w]; const int ii = si[(pw)*16 + w]; \
        const bool better = (v > bv) || ((v == bv) && (ii < bi)); \
        bv = better ? v : bv; bi = better ? ii : bi; \
      } \
      far = bi; \
      const float* __restrict__ cp = P + 3 * (size_t)far; \
      ccx = cp[0]; ccy = cp[1]; ccz = cp[2]; \
      if (tid == 0) { \
        const size_t ob = (size_t)b * NS_ + (ss); \
        outP[ob*3+0] = ccx; outP[ob*3+1] = ccy; outP[ob*3+2] = ccz; \
        idxw[ob] = far; \
      } \
    } while (0)

    // ---- d0 pass ----
    {
      const float cx0 = cent[0], cy0 = cent[1], cz0 = cent[2];
      float lm = -1.0f; int lk = 0;
      #pragma unroll
      for (int k = 0; k < 16; ++k) {
        const int n = k * 1024 + tid;
        const float2 xy = sXY[n];
        const float z = Pv[3*n+2];
        const float d = sqdist_xla(xy.x, xy.y, z, cx0, cy0, cz0);
        dd[k] = d;
        const bool bt = (d > lm);          // ties keep earlier k (smaller n)
        lk = bt ? k : lk; lm = bt ? d : lm;
      }
      const int gi = lk * 1024 + tid;
      SELECT_FAR(0, 0);
    }
    #pragma unroll
    for (int k = 0; k < 16; ++k) dd[k] = 1e10f;   // reference init

    // ---- main loop: one barrier per iteration ----
    for (int s = 1; s < NS_; ++s) {
      float lm = -1.0f; int lk = 0;
      #pragma unroll
      for (int k = 0; k < 16; ++k) {
        const int n = k * 1024 + tid;
        const float2 xy = sXY[n];
        const float z = Pv[3*n+2];         // volatile: fresh coalesced load, never hoisted
        const float d  = sqdist_xla(xy.x, xy.y, z, ccx, ccy, ccz);
        const float nd = fminf(dd[k], d);
        dd[k] = nd;
        const bool bt = (nd > lm);
        lk = bt ? k : lk; lm = bt ? nd : lm;
      }
      const int gi = lk * 1024 + tid;
      SELECT_FAR(s & 1, s);
    }
  } else {
    // ================= Gram (one block per batch, 1024 threads) =================
    float* __restrict__ Lf = (float*)LDSB;     // [32][128]
    const int b = (int)blockIdx.x - B_;
    float acc[4][4];
    #pragma unroll
    for (int i = 0; i < 4; ++i)
      #pragma unroll
      for (int j = 0; j < 4; ++j) acc[i][j] = 0.f;
    float sacc = 0.f;
    const int ti = tid >> 5;   // 0..31
    const int tj = tid & 31;   // 0..31
    const float* fb = features + (size_t)b * N_ * CIN_;
    for (int t32 = 0; t32 < N_/32; ++t32) {
      const float4 v0 = *(const float4*)(fb + ((size_t)t32 * 32 + ti) * CIN_ + tj * 4);
      __syncthreads();
      *(float4*)&Lf[ti*128 + tj*4] = v0;
      __syncthreads();
      #pragma unroll 4
      for (int r = 0; r < 32; ++r) {
        const float4 a4 = *(const float4*)&Lf[r*128 + ti*4];
        const float4 b4 = *(const float4*)&Lf[r*128 + tj*4];
        const float av[4] = {a4.x, a4.y, a4.z, a4.w};
        const float bw[4] = {b4.x, b4.y, b4.z, b4.w};
        #pragma unroll
        for (int i = 0; i < 4; ++i)
          #pragma unroll
          for (int j = 0; j < 4; ++j) acc[i][j] = fmaf(av[i], bw[j], acc[i][j]);
      }
      if (tid < 128) {
        #pragma unroll 8
        for (int r = 0; r < 32; ++r) sacc += Lf[r*128 + tid];
      }
    }
    float* gp = Gred + (size_t)b * (CIN_*CIN_);
    #pragma unroll
    for (int i = 0; i < 4; ++i)
      #pragma unroll
      for (int j = 0; j < 4; ++j)
        gp[(ti*4+i)*CIN_ + tj*4 + j] = acc[i][j];
    if (tid < 128) Sred[b*CIN_ + tid] = sacc;
  }
}

// per (b,o): mu-b = w.S/N ; var = (wGw + 2 b w.S)/N + b^2 - mu^2 ; scale = 1/sqrt(var+eps)
__global__ __launch_bounds__(128) void k2b_stats(
    const float* __restrict__ Gred, const float* __restrict__ Sred,
    const float* __restrict__ W, const float* __restrict__ bias,
    float* __restrict__ stats)
{
  const int b = blockIdx.x >> 8;
  const int o = blockIdx.x & 255;
  const int tid = threadIdx.x;
  __shared__ float sw[CIN_];
  __shared__ float r1[CIN_], r2[CIN_];
  sw[tid] = W[(size_t)o*CIN_ + tid];
  __syncthreads();
  const float* gr = Gred + (size_t)b*CIN_*CIN_ + (size_t)tid*CIN_;
  float g = 0.f;
  #pragma unroll 8
  for (int j = 0; j < CIN_; ++j) g = fmaf(gr[j], sw[j], g);
  r1[tid] = g * sw[tid];
  r2[tid] = sw[tid] * Sred[b*CIN_ + tid];
  __syncthreads();
  for (int stp = 64; stp > 0; stp >>= 1) {
    if (tid < stp) { r1[tid] += r1[tid+stp]; r2[tid] += r2[tid+stp]; }
    __syncthreads();
  }
  if (tid == 0) {
    const float wGw = r1[0], wS = r2[0], bo = bias[o];
    const float invN = 1.0f / (float)N_;
    const float mu  = wS*invN + bo;
    const float ex2 = (wGw + 2.0f*bo*wS)*invN + bo*bo;
    float var = ex2 - mu*mu;
    var = fmaxf(var, 0.0f);
    const float sc = 1.0f / sqrtf(var + 1e-5f);
    stats[((size_t)(b*COUT_ + o))*2 + 0] = wS*invN;  // mu - bias
    stats[((size_t)(b*COUT_ + o))*2 + 1] = sc;
  }
}

// recompute GEMM at sampled rows only, apply norm + relu
__global__ __launch_bounds__(256) void k3_out(
    const float* __restrict__ features, const float* __restrict__ W,
    const int* __restrict__ idxw, const float* __restrict__ stats,
    float* __restrict__ outF)
{
  const int tid = threadIdx.x;
  const int b  = blockIdx.x >> 8;
  const int r  = blockIdx.x & 255;
  const int st = r >> 2, ot = r & 3;
  const int s0 = st * 64, o0 = ot * 64;

  __shared__ float Fs[64][129];
  __shared__ float Wt[64][129];
  __shared__ int   sIdx[64];
  __shared__ float sSub[64], sSc[64];

  if (tid < 64) sIdx[tid] = idxw[b*NS_ + s0 + tid];
  if (tid >= 64 && tid < 128) {
    const int oo = tid - 64;
    sSub[oo] = stats[((size_t)(b*COUT_ + o0 + oo))*2 + 0];
    sSc[oo]  = stats[((size_t)(b*COUT_ + o0 + oo))*2 + 1];
  }
  __syncthreads();
  {
    const int row = tid >> 2;   // 0..63
    const int q   = tid & 3;
    const float* fsrc = features + ((size_t)b*N_ + sIdx[row]) * CIN_;
    const float* wsrc = W + (size_t)(o0 + row) * CIN_;
    #pragma unroll
    for (int v = 0; v < 8; ++v) {
      const int c = q*4 + v*16;
      const float4 fv = *(const float4*)(fsrc + c);
      const float4 wv = *(const float4*)(wsrc + c);
      Fs[row][c+0]=fv.x; Fs[row][c+1]=fv.y; Fs[row][c+2]=fv.z; Fs[row][c+3]=fv.w;
      Wt[row][c+0]=wv.x; Wt[row][c+1]=wv.y; Wt[row][c+2]=wv.z; Wt[row][c+3]=wv.w;
    }
  }
  __syncthreads();

  const int ts = tid >> 4, to = tid & 15;
  float acc[4][4];
  #pragma unroll
  for (int i = 0; i < 4; ++i)
    #pragma unroll
    for (int j = 0; j < 4; ++j) acc[i][j] = 0.f;

  #pragma unroll 4
  for (int k = 0; k < CIN_; ++k) {
    const float a0 = Fs[ts*4+0][k], a1 = Fs[ts*4+1][k], a2 = Fs[ts*4+2][k], a3 = Fs[ts*4+3][k];
    const float w0 = Wt[to*4+0][k], w1 = Wt[to*4+1][k], w2 = Wt[to*4+2][k], w3 = Wt[to*4+3][k];
    acc[0][0]=fmaf(a0,w0,acc[0][0]); acc[0][1]=fmaf(a0,w1,acc[0][1]); acc[0][2]=fmaf(a0,w2,acc[0][2]); acc[0][3]=fmaf(a0,w3,acc[0][3]);
    acc[1][0]=fmaf(a1,w0,acc[1][0]); acc[1][1]=fmaf(a1,w1,acc[1][1]); acc[1][2]=fmaf(a1,w2,acc[1][2]); acc[1][3]=fmaf(a1,w3,acc[1][3]);
    acc[2][0]=fmaf(a2,w0,acc[2][0]); acc[2][1]=fmaf(a2,w1,acc[2][1]); acc[2][2]=fmaf(a2,w2,acc[2][2]); acc[2][3]=fmaf(a2,w3,acc[2][3]);
    acc[3][0]=fmaf(a3,w0,acc[3][0]); acc[3][1]=fmaf(a3,w1,acc[3][1]); acc[3][2]=fmaf(a3,w2,acc[3][2]); acc[3][3]=fmaf(a3,w3,acc[3][3]);
  }

  #pragma unroll
  for (int i = 0; i < 4; ++i) {
    float4 o4;
    o4.x = fmaxf((acc[i][0] - sSub[to*4+0]) * sSc[to*4+0], 0.f);
    o4.y = fmaxf((acc[i][1] - sSub[to*4+1]) * sSc[to*4+1], 0.f);
    o4.z = fmaxf((acc[i][2] - sSub[to*4+2]) * sSc[to*4+2], 0.f);
    o4.w = fmaxf((acc[i][3] - sSub[to*4+3]) * sSc[to*4+3], 0.f);
    *(float4*)&outF[((size_t)b*NS_ + s0 + ts*4 + i)*COUT_ + o0 + to*4] = o4;
  }
}

extern "C" void kernel_launch(void* const* d_in, const int* in_sizes, int n_in,
                              void* d_out, int out_size, void* d_ws, size_t ws_size,
                              hipStream_t stream) {
  (void)in_sizes; (void)n_in; (void)out_size; (void)ws_size;
  const float* points   = (const float*)d_in[0];
  const float* features = (const float*)d_in[1];
  const float* W        = (const float*)d_in[2];
  const float* bias     = (const float*)d_in[3];
  float* out  = (float*)d_out;
  float* outP = out;
  float* outF = out + (size_t)B_*NS_*3;

  char* ws = (char*)d_ws;
  int*   idxw  = (int*)  (ws + 0);        // 131072 B
  float* Gred  = (float*)(ws + 131072);   // 524288 B
  float* Sred  = (float*)(ws + 655360);   // 4096 B
  float* stats = (float*)(ws + 659456);   // 16384 B

  k1_fps_gram<<<dim3(B_ + B_),  dim3(1024), 0, stream>>>(points, features, outP, idxw, Gred, Sred);
  k2b_stats  <<<dim3(B_*COUT_), dim3(CIN_), 0, stream>>>(Gred, Sred, W, bias, stats);
  k3_out     <<<dim3(B_*256),   dim3(256),  0, stream>>>(features, W, idxw, stats, outF);
}

// Round 13
// 6560.205 us; speedup vs baseline: 2.3845x; 2.3845x over previous
//
#include <hip/hip_runtime.h>
#include <math.h>

#define B_      8
#define N_      16384
#define CIN_    128
#define COUT_   256
#define NS_     4096

// XLA-CPU-contracted distance: fma(dz,dz, fma(dy,dy, dx*dx)) — bit-exact vs gold.
static __device__ __forceinline__ float sqdist_xla(float px, float py, float pz,
                                                   float cx, float cy, float cz) {
  float dx = __fsub_rn(px, cx);
  float dy = __fsub_rn(py, cy);
  float dz = __fsub_rn(pz, cz);
  return __fmaf_rn(dz, dz, __fmaf_rn(dy, dy, __fmul_rn(dx, dx)));
}

// Blocks 0..7: FPS — xy in LDS (identity layout n=k*1024+tid), z+dd in regs.
// Value-only scan; argmax index discovered post-hoc by the (rare) matching wave.
// Blocks 8..15: full Gram G = F^T F + column sums S per batch (hidden under FPS).
__global__ __launch_bounds__(1024) void k1_fps_gram(
    const float* __restrict__ points, const float* __restrict__ features,
    float* __restrict__ outP, int* __restrict__ idxw,
    float* __restrict__ Gred, float* __restrict__ Sred)
{
  __shared__ __align__(16) char LDSB[131072 + 128];
  const int tid = threadIdx.x;

  if (blockIdx.x < B_) {
    // ================= FPS =================
    const int b = blockIdx.x;
    const float* __restrict__ P = points + (size_t)b * N_ * 3;
    float2*   __restrict__ sXY  = (float2*)LDSB;                    // [16384]
    float*    __restrict__ sv   = (float*)(LDSB + 131072);          // [16]
    unsigned* __restrict__ cellI= (unsigned*)(LDSB + 131072 + 64);  // [2]
    float*    __restrict__ cent = (float*)(LDSB + 131072 + 80);
    const int lane = tid & 63;
    const int wid  = tid >> 6;    // 0..15

    // stage xy -> LDS (coalesced), z -> regs
    float z_[16];
    #pragma unroll
    for (int k = 0; k < 16; ++k) {
      const int n = k * 1024 + tid;
      sXY[n] = make_float2(P[3*n+0], P[3*n+1]);
      z_[k]  = P[3*n+2];
    }
    #pragma unroll
    for (int k = 0; k < 16; ++k) asm volatile("" : "+v"(z_[k]));

    // centroid: strict sequential f32 (reference emission order), *2^-14 exact
    if (tid < 3) {
      const int c = tid;
      float acc = P[c];
      for (int n = 1; n < N_; ++n) acc = __fadd_rn(acc, P[3*n + c]);
      cent[c] = __fmul_rn(acc, 6.103515625e-05f);
    }
    if (tid == 0) { cellI[0] = 0xFFFFFFFFu; cellI[1] = 0xFFFFFFFFu; }
    __syncthreads();

    float dd[16];
    float ccx, ccy, ccz;

    // ---- d0 pass (uses cellI[0]) ----
    {
      const float cx0 = cent[0], cy0 = cent[1], cz0 = cent[2];
      float tlm = -1.0f;
      #pragma unroll
      for (int k = 0; k < 16; ++k) {
        const int n = k * 1024 + tid;
        const float2 xy = sXY[n];
        const float d = sqdist_xla(xy.x, xy.y, z_[k], cx0, cy0, cz0);
        dd[k] = d;
        tlm = fmaxf(tlm, d);
      }
      float wlm = tlm;
      #pragma unroll
      for (int off = 32; off > 0; off >>= 1) wlm = fmaxf(wlm, __shfl_xor(wlm, off));
      if (lane == 0) sv[wid] = wlm;
      __syncthreads();                               // B1
      float bv = sv[0];
      #pragma unroll
      for (int w = 1; w < 16; ++w) bv = fmaxf(bv, sv[w]);
      if (tlm == bv) {                               // rare wave: recover min index
        int kb = 0x7FFFFFFF;
        #pragma unroll
        for (int k = 15; k >= 0; --k) kb = (dd[k] == bv) ? k : kb;
        atomicMin(&cellI[0], (unsigned)(kb * 1024 + tid));
      }
      __syncthreads();                               // B2
      const int far = (int)cellI[0];
      const float2 xy = sXY[far];
      ccx = xy.x; ccy = xy.y; ccz = P[3*(size_t)far + 2];
      if (tid == 0) {
        const size_t ob = (size_t)b * NS_;
        outP[ob*3+0] = ccx; outP[ob*3+1] = ccy; outP[ob*3+2] = ccz;
        idxw[ob] = far;
      }
    }
    #pragma unroll
    for (int k = 0; k < 16; ++k) dd[k] = 1e10f;      // reference init

    // ---- main loop: scan is value-only; 2 barriers/iter ----
    for (int s = 1; s < NS_; ++s) {
      const int par = s & 1;
      float tlm = -1.0f;
      #pragma unroll
      for (int k = 0; k < 16; ++k) {
        const int n = k * 1024 + tid;
        const float2 xy = sXY[n];
        const float d  = sqdist_xla(xy.x, xy.y, z_[k], ccx, ccy, ccz);
        const float nd = fminf(dd[k], d);
        dd[k] = nd;
        tlm = fmaxf(tlm, nd);
      }
      float wlm = tlm;
      #pragma unroll
      for (int off = 32; off > 0; off >>= 1) wlm = fmaxf(wlm, __shfl_xor(wlm, off));
      if (lane == 0) sv[wid] = wlm;
      __syncthreads();                               // B1
      float bv = sv[0];
      #pragma unroll
      for (int w = 1; w < 16; ++w) bv = fmaxf(bv, sv[w]);
      if (tid == 0) cellI[par ^ 1] = 0xFFFFFFFFu;    // reset other cell (barrier-separated)
      if (tlm == bv) {
        int kb = 0x7FFFFFFF;
        #pragma unroll
        for (int k = 15; k >= 0; --k) kb = (dd[k] == bv) ? k : kb;
        atomicMin(&cellI[par], (unsigned)(kb * 1024 + tid));
      }
      __syncthreads();                               // B2
      const int far = (int)cellI[par];
      const float2 xy = sXY[far];
      ccx = xy.x; ccy = xy.y; ccz = P[3*(size_t)far + 2];
      if (tid == 0) {
        const size_t ob = (size_t)b * NS_ + s;
        outP[ob*3+0] = ccx; outP[ob*3+1] = ccy; outP[ob*3+2] = ccz;
        idxw[ob] = far;
      }
    }
  } else {
    // ================= Gram (one block per batch, 1024 threads) =================
    float* __restrict__ Lf = (float*)LDSB;     // [32][128]
    const int b = (int)blockIdx.x - B_;
    float acc[4][4];
    #pragma unroll
    for (int i = 0; i < 4; ++i)
      #pragma unroll
      for (int j = 0; j < 4; ++j) acc[i][j] = 0.f;
    float sacc = 0.f;
    const int ti = tid >> 5;   // 0..31
    const int tj = tid & 31;   // 0..31
    const float* fb = features + (size_t)b * N_ * CIN_;
    for (int t32 = 0; t32 < N_/32; ++t32) {
      const float4 v0 = *(const float4*)(fb + ((size_t)t32 * 32 + ti) * CIN_ + tj * 4);
      __syncthreads();
      *(float4*)&Lf[ti*128 + tj*4] = v0;
      __syncthreads();
      #pragma unroll 4
      for (int r = 0; r < 32; ++r) {
        const float4 a4 = *(const float4*)&Lf[r*128 + ti*4];
        const float4 b4 = *(const float4*)&Lf[r*128 + tj*4];
        const float av[4] = {a4.x, a4.y, a4.z, a4.w};
        const float bw[4] = {b4.x, b4.y, b4.z, b4.w};
        #pragma unroll
        for (int i = 0; i < 4; ++i)
          #pragma unroll
          for (int j = 0; j < 4; ++j) acc[i][j] = fmaf(av[i], bw[j], acc[i][j]);
      }
      if (tid < 128) {
        #pragma unroll 8
        for (int r = 0; r < 32; ++r) sacc += Lf[r*128 + tid];
      }
    }
    float* gp = Gred + (size_t)b * (CIN_*CIN_);
    #pragma unroll
    for (int i = 0; i < 4; ++i)
      #pragma unroll
      for (int j = 0; j < 4; ++j)
        gp[(ti*4+i)*CIN_ + tj*4 + j] = acc[i][j];
    if (tid < 128) Sred[b*CIN_ + tid] = sacc;
  }
}

// per (b,o): mu-b = w.S/N ; var = (wGw + 2 b w.S)/N + b^2 - mu^2 ; scale = 1/sqrt(var+eps)
__global__ __launch_bounds__(128) void k2b_stats(
    const float* __restrict__ Gred, const float* __restrict__ Sred,
    const float* __restrict__ W, const float* __restrict__ bias,
    float* __restrict__ stats)
{
  const int b = blockIdx.x >> 8;
  const int o = blockIdx.x & 255;
  const int tid = threadIdx.x;
  __shared__ float sw[CIN_];
  __shared__ float r1[CIN_], r2[CIN_];
  sw[tid] = W[(size_t)o*CIN_ + tid];
  __syncthreads();
  const float* gr = Gred + (size_t)b*CIN_*CIN_ + (size_t)tid*CIN_;
  float g = 0.f;
  #pragma unroll 8
  for (int j = 0; j < CIN_; ++j) g = fmaf(gr[j], sw[j], g);
  r1[tid] = g * sw[tid];
  r2[tid] = sw[tid] * Sred[b*CIN_ + tid];
  __syncthreads();
  for (int stp = 64; stp > 0; stp >>= 1) {
    if (tid < stp) { r1[tid] += r1[tid+stp]; r2[tid] += r2[tid+stp]; }
    __syncthreads();
  }
  if (tid == 0) {
    const float wGw = r1[0], wS = r2[0], bo = bias[o];
    const float invN = 1.0f / (float)N_;
    const float mu  = wS*invN + bo;
    const float ex2 = (wGw + 2.0f*bo*wS)*invN + bo*bo;
    float var = ex2 - mu*mu;
    var = fmaxf(var, 0.0f);
    const float sc = 1.0f / sqrtf(var + 1e-5f);
    stats[((size_t)(b*COUT_ + o))*2 + 0] = wS*invN;  // mu - bias
    stats[((size_t)(b*COUT_ + o))*2 + 1] = sc;
  }
}

// recompute GEMM at sampled rows only, apply norm + relu
__global__ __launch_bounds__(256) void k3_out(
    const float* __restrict__ features, const float* __restrict__ W,
    const int* __restrict__ idxw, const float* __restrict__ stats,
    float* __restrict__ outF)
{
  const int tid = threadIdx.x;
  const int b  = blockIdx.x >> 8;
  const int r  = blockIdx.x & 255;
  const int st = r >> 2, ot = r & 3;
  const int s0 = st * 64, o0 = ot * 64;

  __shared__ float Fs[64][129];
  __shared__ float Wt[64][129];
  __shared__ int   sIdx[64];
  __shared__ float sSub[64], sSc[64];

  if (tid < 64) sIdx[tid] = idxw[b*NS_ + s0 + tid];
  if (tid >= 64 && tid < 128) {
    const int oo = tid - 64;
    sSub[oo] = stats[((size_t)(b*COUT_ + o0 + oo))*2 + 0];
    sSc[oo]  = stats[((size_t)(b*COUT_ + o0 + oo))*2 + 1];
  }
  __syncthreads();
  {
    const int row = tid >> 2;   // 0..63
    const int q   = tid & 3;
    const float* fsrc = features + ((size_t)b*N_ + sIdx[row]) * CIN_;
    const float* wsrc = W + (size_t)(o0 + row) * CIN_;
    #pragma unroll
    for (int v = 0; v < 8; ++v) {
      const int c = q*4 + v*16;
      const float4 fv = *(const float4*)(fsrc + c);
      const float4 wv = *(const float4*)(wsrc + c);
      Fs[row][c+0]=fv.x; Fs[row][c+1]=fv.y; Fs[row][c+2]=fv.z; Fs[row][c+3]=fv.w;
      Wt[row][c+0]=wv.x; Wt[row][c+1]=wv.y; Wt[row][c+2]=wv.z; Wt[row][c+3]=wv.w;
    }
  }
  __syncthreads();

  const int ts = tid >> 4, to = tid & 15;
  float acc[4][4];
  #pragma unroll
  for (int i = 0; i < 4; ++i)
    #pragma unroll
    for (int j = 0; j < 4; ++j) acc[i][j] = 0.f;

  #pragma unroll 4
  for (int k = 0; k < CIN_; ++k) {
    const float a0 = Fs[ts*4+0][k], a1 = Fs[ts*4+1][k], a2 = Fs[ts*4+2][k], a3 = Fs[ts*4+3][k];
    const float w0 = Wt[to*4+0][k], w1 = Wt[to*4+1][k], w2 = Wt[to*4+2][k], w3 = Wt[to*4+3][k];
    acc[0][0]=fmaf(a0,w0,acc[0][0]); acc[0][1]=fmaf(a0,w1,acc[0][1]); acc[0][2]=fmaf(a0,w2,acc[0][2]); acc[0][3]=fmaf(a0,w3,acc[0][3]);
    acc[1][0]=fmaf(a1,w0,acc[1][0]); acc[1][1]=fmaf(a1,w1,acc[1][1]); acc[1][2]=fmaf(a1,w2,acc[1][2]); acc[1][3]=fmaf(a1,w3,acc[1][3]);
    acc[2][0]=fmaf(a2,w0,acc[2][0]); acc[2][1]=fmaf(a2,w1,acc[2][1]); acc[2][2]=fmaf(a2,w2,acc[2][2]); acc[2][3]=fmaf(a2,w3,acc[2][3]);
    acc[3][0]=fmaf(a3,w0,acc[3][0]); acc[3][1]=fmaf(a3,w1,acc[3][1]); acc[3][2]=fmaf(a3,w2,acc[3][2]); acc[3][3]=fmaf(a3,w3,acc[3][3]);
  }

  #pragma unroll
  for (int i = 0; i < 4; ++i) {
    float4 o4;
    o4.x = fmaxf((acc[i][0] - sSub[to*4+0]) * sSc[to*4+0], 0.f);
    o4.y = fmaxf((acc[i][1] - sSub[to*4+1]) * sSc[to*4+1], 0.f);
    o4.z = fmaxf((acc[i][2] - sSub[to*4+2]) * sSc[to*4+2], 0.f);
    o4.w = fmaxf((acc[i][3] - sSub[to*4+3]) * sSc[to*4+3], 0.f);
    *(float4*)&outF[((size_t)b*NS_ + s0 + ts*4 + i)*COUT_ + o0 + to*4] = o4;
  }
}

extern "C" void kernel_launch(void* const* d_in, const int* in_sizes, int n_in,
                              void* d_out, int out_size, void* d_ws, size_t ws_size,
                              hipStream_t stream) {
  (void)in_sizes; (void)n_in; (void)out_size; (void)ws_size;
  const float* points   = (const float*)d_in[0];
  const float* features = (const float*)d_in[1];
  const float* W        = (const float*)d_in[2];
  const float* bias     = (const float*)d_in[3];
  float* out  = (float*)d_out;
  float* outP = out;
  float* outF = out + (size_t)B_*NS_*3;

  char* ws = (char*)d_ws;
  int*   idxw  = (int*)  (ws + 0);        // 131072 B
  float* Gred  = (float*)(ws + 131072);   // 524288 B
  float* Sred  = (float*)(ws + 655360);   // 4096 B
  float* stats = (float*)(ws + 659456);   // 16384 B

  k1_fps_gram<<<dim3(B_ + B_),  dim3(1024), 0, stream>>>(points, features, outP, idxw, Gred, Sred);
  k2b_stats  <<<dim3(B_*COUT_), dim3(CIN_), 0, stream>>>(Gred, Sred, W, bias, stats);
  k3_out     <<<dim3(B_*256),   dim3(256),  0, stream>>>(features, W, idxw, stats, outF);
}

// Round 14
// 5913.123 us; speedup vs baseline: 2.6455x; 1.1094x over previous
//
#include <hip/hip_runtime.h>
#include <math.h>

#define B_      8
#define N_      16384
#define CIN_    128
#define COUT_   256
#define NS_     4096

typedef unsigned long long u64;

// XLA-CPU-contracted distance: fma(dz,dz, fma(dy,dy, dx*dx)) — bit-exact vs gold.
static __device__ __forceinline__ float sqdist_xla(float px, float py, float pz,
                                                   float cx, float cy, float cz) {
  float dx = __fsub_rn(px, cx);
  float dy = __fsub_rn(py, cy);
  float dz = __fsub_rn(pz, cz);
  return __fmaf_rn(dz, dz, __fmaf_rn(dy, dy, __fmul_rn(dx, dx)));
}

// Canonical GCN wave64 max-reduce via DPP; valid result in lane 63.
// old=0 fill is safe: all inputs are non-negative (squared distances / 1e10).
static __device__ __forceinline__ float wave64_max_dpp(float x) {
  int v = __float_as_int(x);
  #define DPPSTEP(ctrl, rm, bm) { \
    const int t = __builtin_amdgcn_update_dpp(0, v, (ctrl), (rm), (bm), false); \
    v = __float_as_int(fmaxf(__int_as_float(v), __int_as_float(t))); }
  DPPSTEP(0x111, 0xf, 0xf)   // row_shr:1
  DPPSTEP(0x112, 0xf, 0xf)   // row_shr:2
  DPPSTEP(0x114, 0xf, 0xe)   // row_shr:4
  DPPSTEP(0x118, 0xf, 0xc)   // row_shr:8
  DPPSTEP(0x142, 0xa, 0xf)   // row_bcast:15
  DPPSTEP(0x143, 0xc, 0xf)   // row_bcast:31
  #undef DPPSTEP
  return __int_as_float(v);
}

// Blocks 0..7: FPS — xy in LDS, z+dd in regs; DPP wave max; LDS atomics carry
// (value) and (index,z) so no global load sits on the per-iteration chain.
// Blocks 8..15: full Gram G = F^T F + column sums S per batch.
__global__ __launch_bounds__(1024) void k1_fps_gram(
    const float* __restrict__ points, const float* __restrict__ features,
    float* __restrict__ outP, int* __restrict__ idxw,
    float* __restrict__ Gred, float* __restrict__ Sred)
{
  __shared__ __align__(16) char LDSB[131072 + 128];
  const int tid = threadIdx.x;

  if (blockIdx.x < B_) {
    // ================= FPS =================
    const int b = blockIdx.x;
    const float* __restrict__ P = points + (size_t)b * N_ * 3;
    float2*   __restrict__ sXY   = (float2*)LDSB;                    // [16384]
    u64*      __restrict__ cellI = (u64*)(LDSB + 131072);            // [2]
    unsigned* __restrict__ cellV = (unsigned*)(LDSB + 131072 + 16);  // [2]
    float*    __restrict__ cent  = (float*)(LDSB + 131072 + 24);
    const int lane = tid & 63;

    // stage xy -> LDS (coalesced), z -> regs
    float z_[16];
    #pragma unroll
    for (int k = 0; k < 16; ++k) {
      const int n = k * 1024 + tid;
      sXY[n] = make_float2(P[3*n+0], P[3*n+1]);
      z_[k]  = P[3*n+2];
    }
    #pragma unroll
    for (int k = 0; k < 16; ++k) asm volatile("" : "+v"(z_[k]));

    // centroid: strict sequential f32 (reference emission order), *2^-14 exact
    if (tid < 3) {
      const int c = tid;
      float acc = P[c];
      for (int n = 1; n < N_; ++n) acc = __fadd_rn(acc, P[3*n + c]);
      cent[c] = __fmul_rn(acc, 6.103515625e-05f);
    }
    if (tid == 0) {
      cellI[0] = ~0ULL; cellI[1] = ~0ULL;
      cellV[0] = 0u;    cellV[1] = 0u;
    }
    __syncthreads();

    float dd[16];
    float ccx, ccy, ccz;

    // ---- d0 pass (par = 0) ----
    {
      const float cx0 = cent[0], cy0 = cent[1], cz0 = cent[2];
      float tlm = -1.0f;
      #pragma unroll
      for (int k = 0; k < 16; ++k) {
        const int n = k * 1024 + tid;
        const float2 xy = sXY[n];
        const float d = sqdist_xla(xy.x, xy.y, z_[k], cx0, cy0, cz0);
        dd[k] = d;
        tlm = fmaxf(tlm, d);
      }
      const float wlm = wave64_max_dpp(tlm);
      if (lane == 63) atomicMax(&cellV[0], (unsigned)__float_as_int(wlm));
      __syncthreads();                               // B1
      const float bv = __int_as_float((int)cellV[0]);
      if (tid == 0) { cellV[1] = 0u; cellI[1] = ~0ULL; }
      if (tlm == bv) {                               // rare thread: recover min index + z
        int kb = 0x7FFFFFFF;
        #pragma unroll
        for (int k = 15; k >= 0; --k) kb = (dd[k] == bv) ? k : kb;
        float zz = z_[0];
        #pragma unroll
        for (int k = 1; k < 16; ++k) zz = (kb == k) ? z_[k] : zz;
        const u64 key = ((u64)(unsigned)(kb * 1024 + tid) << 32)
                      | (u64)(unsigned)__float_as_int(zz);
        atomicMin(&cellI[0], key);
      }
      __syncthreads();                               // B2
      const u64 cw = cellI[0];
      const int far = (int)(cw >> 32);
      ccz = __int_as_float((int)(unsigned)cw);
      const float2 xy = sXY[far];
      ccx = xy.x; ccy = xy.y;
      if (tid == 0) {
        const size_t ob = (size_t)b * NS_;
        outP[ob*3+0] = ccx; outP[ob*3+1] = ccy; outP[ob*3+2] = ccz;
        idxw[ob] = far;
      }
    }
    #pragma unroll
    for (int k = 0; k < 16; ++k) dd[k] = 1e10f;      // reference init

    // ---- main loop: 2 barriers/iter, no global loads on the chain ----
    for (int s = 1; s < NS_; ++s) {
      const int par = s & 1;
      float tlm = -1.0f;
      #pragma unroll
      for (int k = 0; k < 16; ++k) {
        const int n = k * 1024 + tid;
        const float2 xy = sXY[n];
        const float d  = sqdist_xla(xy.x, xy.y, z_[k], ccx, ccy, ccz);
        const float nd = fminf(dd[k], d);
        dd[k] = nd;
        tlm = fmaxf(tlm, nd);
      }
      const float wlm = wave64_max_dpp(tlm);
      if (lane == 63) atomicMax(&cellV[par], (unsigned)__float_as_int(wlm));
      __syncthreads();                               // B1
      const float bv = __int_as_float((int)cellV[par]);
      if (tid == 0) { cellV[par ^ 1] = 0u; cellI[par ^ 1] = ~0ULL; }  // barrier-separated reset
      if (tlm == bv) {
        int kb = 0x7FFFFFFF;
        #pragma unroll
        for (int k = 15; k >= 0; --k) kb = (dd[k] == bv) ? k : kb;
        float zz = z_[0];
        #pragma unroll
        for (int k = 1; k < 16; ++k) zz = (kb == k) ? z_[k] : zz;
        const u64 key = ((u64)(unsigned)(kb * 1024 + tid) << 32)
                      | (u64)(unsigned)__float_as_int(zz);
        atomicMin(&cellI[par], key);
      }
      __syncthreads();                               // B2
      const u64 cw = cellI[par];
      const int far = (int)(cw >> 32);
      ccz = __int_as_float((int)(unsigned)cw);
      const float2 xy = sXY[far];
      ccx = xy.x; ccy = xy.y;
      if (tid == 0) {
        const size_t ob = (size_t)b * NS_ + s;
        outP[ob*3+0] = ccx; outP[ob*3+1] = ccy; outP[ob*3+2] = ccz;
        idxw[ob] = far;
      }
    }
  } else {
    // ================= Gram (one block per batch, 1024 threads) =================
    float* __restrict__ Lf = (float*)LDSB;     // [32][128]
    const int b = (int)blockIdx.x - B_;
    float acc[4][4];
    #pragma unroll
    for (int i = 0; i < 4; ++i)
      #pragma unroll
      for (int j = 0; j < 4; ++j) acc[i][j] = 0.f;
    float sacc = 0.f;
    const int ti = tid >> 5;   // 0..31
    const int tj = tid & 31;   // 0..31
    const float* fb = features + (size_t)b * N_ * CIN_;
    for (int t32 = 0; t32 < N_/32; ++t32) {
      const float4 v0 = *(const float4*)(fb + ((size_t)t32 * 32 + ti) * CIN_ + tj * 4);
      __syncthreads();
      *(float4*)&Lf[ti*128 + tj*4] = v0;
      __syncthreads();
      #pragma unroll 4
      for (int r = 0; r < 32; ++r) {
        const float4 a4 = *(const float4*)&Lf[r*128 + ti*4];
        const float4 b4 = *(const float4*)&Lf[r*128 + tj*4];
        const float av[4] = {a4.x, a4.y, a4.z, a4.w};
        const float bw[4] = {b4.x, b4.y, b4.z, b4.w};
        #pragma unroll
        for (int i = 0; i < 4; ++i)
          #pragma unroll
          for (int j = 0; j < 4; ++j) acc[i][j] = fmaf(av[i], bw[j], acc[i][j]);
      }
      if (tid < 128) {
        #pragma unroll 8
        for (int r = 0; r < 32; ++r) sacc += Lf[r*128 + tid];
      }
    }
    float* gp = Gred + (size_t)b * (CIN_*CIN_);
    #pragma unroll
    for (int i = 0; i < 4; ++i)
      #pragma unroll
      for (int j = 0; j < 4; ++j)
        gp[(ti*4+i)*CIN_ + tj*4 + j] = acc[i][j];
    if (tid < 128) Sred[b*CIN_ + tid] = sacc;
  }
}

// per (b,o): mu-b = w.S/N ; var = (wGw + 2 b w.S)/N + b^2 - mu^2 ; scale = 1/sqrt(var+eps)
__global__ __launch_bounds__(128) void k2b_stats(
    const float* __restrict__ Gred, const float* __restrict__ Sred,
    const float* __restrict__ W, const float* __restrict__ bias,
    float* __restrict__ stats)
{
  const int b = blockIdx.x >> 8;
  const int o = blockIdx.x & 255;
  const int tid = threadIdx.x;
  __shared__ float sw[CIN_];
  __shared__ float r1[CIN_], r2[CIN_];
  sw[tid] = W[(size_t)o*CIN_ + tid];
  __syncthreads();
  const float* gr = Gred + (size_t)b*CIN_*CIN_ + (size_t)tid*CIN_;
  float g = 0.f;
  #pragma unroll 8
  for (int j = 0; j < CIN_; ++j) g = fmaf(gr[j], sw[j], g);
  r1[tid] = g * sw[tid];
  r2[tid] = sw[tid] * Sred[b*CIN_ + tid];
  __syncthreads();
  for (int stp = 64; stp > 0; stp >>= 1) {
    if (tid < stp) { r1[tid] += r1[tid+stp]; r2[tid] += r2[tid+stp]; }
    __syncthreads();
  }
  if (tid == 0) {
    const float wGw = r1[0], wS = r2[0], bo = bias[o];
    const float invN = 1.0f / (float)N_;
    const float mu  = wS*invN + bo;
    const float ex2 = (wGw + 2.0f*bo*wS)*invN + bo*bo;
    float var = ex2 - mu*mu;
    var = fmaxf(var, 0.0f);
    const float sc = 1.0f / sqrtf(var + 1e-5f);
    stats[((size_t)(b*COUT_ + o))*2 + 0] = wS*invN;  // mu - bias
    stats[((size_t)(b*COUT_ + o))*2 + 1] = sc;
  }
}

// recompute GEMM at sampled rows only, apply norm + relu
__global__ __launch_bounds__(256) void k3_out(
    const float* __restrict__ features, const float* __restrict__ W,
    const int* __restrict__ idxw, const float* __restrict__ stats,
    float* __restrict__ outF)
{
  const int tid = threadIdx.x;
  const int b  = blockIdx.x >> 8;
  const int r  = blockIdx.x & 255;
  const int st = r >> 2, ot = r & 3;
  const int s0 = st * 64, o0 = ot * 64;

  __shared__ float Fs[64][129];
  __shared__ float Wt[64][129];
  __shared__ int   sIdx[64];
  __shared__ float sSub[64], sSc[64];

  if (tid < 64) sIdx[tid] = idxw[b*NS_ + s0 + tid];
  if (tid >= 64 && tid < 128) {
    const int oo = tid - 64;
    sSub[oo] = stats[((size_t)(b*COUT_ + o0 + oo))*2 + 0];
    sSc[oo]  = stats[((size_t)(b*COUT_ + o0 + oo))*2 + 1];
  }
  __syncthreads();
  {
    const int row = tid >> 2;   // 0..63
    const int q   = tid & 3;
    const float* fsrc = features + ((size_t)b*N_ + sIdx[row]) * CIN_;
    const float* wsrc = W + (size_t)(o0 + row) * CIN_;
    #pragma unroll
    for (int v = 0; v < 8; ++v) {
      const int c = q*4 + v*16;
      const float4 fv = *(const float4*)(fsrc + c);
      const float4 wv = *(const float4*)(wsrc + c);
      Fs[row][c+0]=fv.x; Fs[row][c+1]=fv.y; Fs[row][c+2]=fv.z; Fs[row][c+3]=fv.w;
      Wt[row][c+0]=wv.x; Wt[row][c+1]=wv.y; Wt[row][c+2]=wv.z; Wt[row][c+3]=wv.w;
    }
  }
  __syncthreads();

  const int ts = tid >> 4, to = tid & 15;
  float acc[4][4];
  #pragma unroll
  for (int i = 0; i < 4; ++i)
    #pragma unroll
    for (int j = 0; j < 4; ++j) acc[i][j] = 0.f;

  #pragma unroll 4
  for (int k = 0; k < CIN_; ++k) {
    const float a0 = Fs[ts*4+0][k], a1 = Fs[ts*4+1][k], a2 = Fs[ts*4+2][k], a3 = Fs[ts*4+3][k];
    const float w0 = Wt[to*4+0][k], w1 = Wt[to*4+1][k], w2 = Wt[to*4+2][k], w3 = Wt[to*4+3][k];
    acc[0][0]=fmaf(a0,w0,acc[0][0]); acc[0][1]=fmaf(a0,w1,acc[0][1]); acc[0][2]=fmaf(a0,w2,acc[0][2]); acc[0][3]=fmaf(a0,w3,acc[0][3]);
    acc[1][0]=fmaf(a1,w0,acc[1][0]); acc[1][1]=fmaf(a1,w1,acc[1][1]); acc[1][2]=fmaf(a1,w2,acc[1][2]); acc[1][3]=fmaf(a1,w3,acc[1][3]);
    acc[2][0]=fmaf(a2,w0,acc[2][0]); acc[2][1]=fmaf(a2,w1,acc[2][1]); acc[2][2]=fmaf(a2,w2,acc[2][2]); acc[2][3]=fmaf(a2,w3,acc[2][3]);
    acc[3][0]=fmaf(a3,w0,acc[3][0]); acc[3][1]=fmaf(a3,w1,acc[3][1]); acc[3][2]=fmaf(a3,w2,acc[3][2]); acc[3][3]=fmaf(a3,w3,acc[3][3]);
  }

  #pragma unroll
  for (int i = 0; i < 4; ++i) {
    float4 o4;
    o4.x = fmaxf((acc[i][0] - sSub[to*4+0]) * sSc[to*4+0], 0.f);
    o4.y = fmaxf((acc[i][1] - sSub[to*4+1]) * sSc[to*4+1], 0.f);
    o4.z = fmaxf((acc[i][2] - sSub[to*4+2]) * sSc[to*4+2], 0.f);
    o4.w = fmaxf((acc[i][3] - sSub[to*4+3]) * sSc[to*4+3], 0.f);
    *(float4*)&outF[((size_t)b*NS_ + s0 + ts*4 + i)*COUT_ + o0 + to*4] = o4;
  }
}

extern "C" void kernel_launch(void* const* d_in, const int* in_sizes, int n_in,
                              void* d_out, int out_size, void* d_ws, size_t ws_size,
                              hipStream_t stream) {
  (void)in_sizes; (void)n_in; (void)out_size; (void)ws_size;
  const float* points   = (const float*)d_in[0];
  const float* features = (const float*)d_in[1];
  const float* W        = (const float*)d_in[2];
  const float* bias     = (const float*)d_in[3];
  float* out  = (float*)d_out;
  float* outP = out;
  float* outF = out + (size_t)B_*NS_*3;

  char* ws = (char*)d_ws;
  int*   idxw  = (int*)  (ws + 0);        // 131072 B
  float* Gred  = (float*)(ws + 131072);   // 524288 B
  float* Sred  = (float*)(ws + 655360);   // 4096 B
  float* stats = (float*)(ws + 659456);   // 16384 B

  k1_fps_gram<<<dim3(B_ + B_),  dim3(1024), 0, stream>>>(points, features, outP, idxw, Gred, Sred);
  k2b_stats  <<<dim3(B_*COUT_), dim3(CIN_), 0, stream>>>(Gred, Sred, W, bias, stats);
  k3_out     <<<dim3(B_*256),   dim3(256),  0, stream>>>(features, W, idxw, stats, outF);
}